// Round 1
// baseline (150.879 us; speedup 1.0000x reference)
//
#include <hip/hip_runtime.h>
#include <hip/hip_bf16.h>
#include <math.h>

#define NFEAT 17
#define DN 20
#define OCH 32
#define H1DIM 500
#define H2DIM 60

// ws layout (float offsets); capacities for n_ele=16384, n_node=8192
#define OFF_G      0        // 16384*17 = 278528
#define OFF_D      278528   // 8192*20  = 163840
#define OFF_SUM    442368   // 32
#define OFF_SSQ    442400   // 32
#define OFF_ACOEF  442432   // 32
#define OFF_COEFC  442464   // 32
#define OFF_WQ     442496   // 288  (c*3+p)*3 + jcls
#define OFF_WP     442784   // 288  (c*3+q)*3 + icls
#define OFF_U      443072   // 500*20
#define OFF_CST    453072   // 500
// total 453572 floats ~= 1.82 MB

// ---------------- K1: g = normalize(mean(oe[node_ele_idx], axis=1)) ----------------
__global__ void k_g(const float* __restrict__ oe, const int* __restrict__ nei,
                    float* __restrict__ g, int n_ele) {
  int e = blockIdx.x * blockDim.x + threadIdx.x;
  if (e >= n_ele) return;
  float acc[NFEAT];
#pragma unroll
  for (int f = 0; f < NFEAT; ++f) acc[f] = 0.f;
#pragma unroll
  for (int m = 0; m < 4; ++m) {
    int a = nei[e * 4 + m];
    const float* row = oe + (size_t)a * NFEAT;
#pragma unroll
    for (int f = 0; f < NFEAT; ++f) acc[f] += row[f];
  }
  float nrm = 0.f;
#pragma unroll
  for (int f = 0; f < NFEAT; ++f) { float v = acc[f] * 0.25f; acc[f] = v; nrm += v * v; }
  float inv = 1.0f / sqrtf(nrm);
#pragma unroll
  for (int f = 0; f < NFEAT; ++f) g[(size_t)e * NFEAT + f] = acc[f] * inv;
}

// ---------------- K2: h = g[i0]+g[i1]; d = distribute(h) ----------------
__global__ void k_d(const float* __restrict__ g, const int* __restrict__ eai,
                    float* __restrict__ dmat, int n_node) {
  int n = blockIdx.x * blockDim.x + threadIdx.x;
  if (n >= n_node) return;
  int i0 = eai[n * 2 + 0], i1 = eai[n * 2 + 1];
  const float* r0 = g + (size_t)i0 * NFEAT;
  const float* r1 = g + (size_t)i1 * NFEAT;
  float s[DN];
#pragma unroll
  for (int k = 0; k < DN; ++k) s[k] = 0.f;
  const float step = 50.0f / 19.0f;
  const float inv2 = 1.0f / (2.0f * 0.3f * 0.3f);
  for (int f = 0; f < NFEAT; ++f) {
    float y = r0[f] + r1[f];
    if (!(y > 0.0f && y < 110.0f)) continue;   // mask
    float ek[DN];
    float m = 0.f;
#pragma unroll
    for (int k = 0; k < DN; ++k) {
      float t = step * (float)k - y;
      ek[k] = __expf(-t * t * inv2);
      m = fmaxf(m, ek[k]);
    }
    if (m > 0.f) {
      float im = 1.0f / m;
#pragma unroll
      for (int k = 0; k < DN; ++k) s[k] += ek[k] * im;
    }
  }
  float smax = 0.f;
#pragma unroll
  for (int k = 0; k < DN; ++k) smax = fmaxf(smax, s[k]);
  float ism = (smax > 0.f) ? 1.0f / smax : 1.0f;
#pragma unroll
  for (int k = 0; k < DN; ++k) dmat[(size_t)n * DN + k] = s[k] * ism;
}

// ---------------- K3: per-channel conv sum / sumsq (BN batch stats) ----------------
// block = 256 threads = 8 nodes x 32 channels. Separable interior + masked edges.
__global__ __launch_bounds__(256) void k_stats(const float* __restrict__ dmat,
                                               const float* __restrict__ convw,
                                               const float* __restrict__ convb,
                                               float* __restrict__ gsum,
                                               float* __restrict__ gssq, int n_node) {
  __shared__ float dd[8][DN];
  int tid = threadIdx.x;
  int ln = tid >> 5, c = tid & 31;
  int n = blockIdx.x * 8 + ln;
  if (tid < 8 * DN) {
    int l2 = tid / DN, a = tid % DN;
    int nn = blockIdx.x * 8 + l2;
    dd[l2][a] = (nn < n_node) ? dmat[(size_t)nn * DN + a] : 0.f;
  }
  __syncthreads();

  float wloc[3][3];
#pragma unroll
  for (int p = 0; p < 3; ++p)
#pragma unroll
    for (int q = 0; q < 3; ++q) wloc[p][q] = convw[c * 9 + p * 3 + q];
  float rwf[3];
#pragma unroll
  for (int p = 0; p < 3; ++p) rwf[p] = wloc[p][0] + wloc[p][1] + wloc[p][2];
  float bias = convb[c];

  float sum = 0.f, sq = 0.f;
  if (n < n_node) {
    for (int i = 0; i < DN; ++i) {
      bool va[3];
      float da[3];
#pragma unroll
      for (int p = 0; p < 3; ++p) {
        int ii = i - 1 + p;
        va[p] = ((unsigned)ii < (unsigned)DN);
        da[p] = va[p] ? dd[ln][ii] : 0.f;
      }
      float rowc = bias;
      float cq0 = 0.f, cq1 = 0.f, cq2 = 0.f;
#pragma unroll
      for (int p = 0; p < 3; ++p) {
        if (va[p]) {
          rowc += rwf[p] * da[p];
          cq0 += wloc[p][0]; cq1 += wloc[p][1]; cq2 += wloc[p][2];
        }
      }
      // j = 0 (q=0 invalid)
      {
        float acc = bias;
#pragma unroll
        for (int p = 0; p < 3; ++p)
          if (va[p]) acc += (wloc[p][1] + wloc[p][2]) * da[p];
        acc += cq1 * dd[ln][0] + cq2 * dd[ln][1];
        sum += acc; sq += acc * acc;
      }
      // j = 1..18 (all q valid)
      float b0 = dd[ln][0], b1v = dd[ln][1];
      for (int j = 1; j < DN - 1; ++j) {
        float b2v = dd[ln][j + 1];
        float acc = rowc + cq0 * b0 + cq1 * b1v + cq2 * b2v;
        sum += acc; sq += acc * acc;
        b0 = b1v; b1v = b2v;
      }
      // j = 19 (q=2 invalid); here b0=dd[18], b1v=dd[19]
      {
        float acc = bias;
#pragma unroll
        for (int p = 0; p < 3; ++p)
          if (va[p]) acc += (wloc[p][0] + wloc[p][1]) * da[p];
        acc += cq0 * b0 + cq1 * b1v;
        sum += acc; sq += acc * acc;
      }
    }
  }
  __shared__ float rs[256], rq[256];
  rs[tid] = sum; rq[tid] = sq;
  __syncthreads();
  if (tid < 32) {
    float a = 0.f, b = 0.f;
#pragma unroll
    for (int k = 0; k < 8; ++k) { a += rs[tid + 32 * k]; b += rq[tid + 32 * k]; }
    atomicAdd(&gsum[tid], a);
    atomicAdd(&gssq[tid], b);
  }
}

// ---------------- K4a: BN coefs + masked tap-row sums ----------------
__global__ void k_coef(const float* __restrict__ gsum, const float* __restrict__ gssq,
                       const float* __restrict__ convw, const float* __restrict__ convb,
                       const float* __restrict__ gamma, const float* __restrict__ beta,
                       float* __restrict__ acoef, float* __restrict__ coefc,
                       float* __restrict__ wq, float* __restrict__ wp, int n_node) {
  int c = threadIdx.x;
  if (c >= OCH) return;
  float invN = 1.0f / ((float)n_node * (float)(DN * DN));
  float mu = gsum[c] * invN;
  float var = gssq[c] * invN - mu * mu;
  float a = gamma[c] / sqrtf(var + 1e-5f);
  acoef[c] = a;
  coefc[c] = a * (convb[c] - mu) + beta[c];
#pragma unroll
  for (int p = 0; p < 3; ++p) {
    float w0 = convw[c * 9 + p * 3 + 0];
    float w1 = convw[c * 9 + p * 3 + 1];
    float w2 = convw[c * 9 + p * 3 + 2];
    wq[(c * 3 + p) * 3 + 0] = w1 + w2;       // j==0: q=0 invalid
    wq[(c * 3 + p) * 3 + 1] = w0 + w1 + w2;  // interior
    wq[(c * 3 + p) * 3 + 2] = w0 + w1;       // j==19: q=2 invalid
  }
#pragma unroll
  for (int q = 0; q < 3; ++q) {
    float w0 = convw[c * 9 + 0 * 3 + q];
    float w1 = convw[c * 9 + 1 * 3 + q];
    float w2 = convw[c * 9 + 2 * 3 + q];
    wp[(c * 3 + q) * 3 + 0] = w1 + w2;       // i==0: p=0 invalid
    wp[(c * 3 + q) * 3 + 1] = w0 + w1 + w2;
    wp[(c * 3 + q) * 3 + 2] = w0 + w1;       // i==19: p=2 invalid
  }
}

// ---------------- K4b: collapse conv+BN+FC1 weights: U[o,a], Cst[o] ----------------
// one block per o; 400 active threads, one per (i,j); reads w1 row exactly once.
__global__ __launch_bounds__(512) void k_buildU(const float* __restrict__ w1,
                                                const float* __restrict__ b1,
                                                const float* __restrict__ acoef,
                                                const float* __restrict__ coefc,
                                                const float* __restrict__ wq,
                                                const float* __restrict__ wp,
                                                float* __restrict__ U,
                                                float* __restrict__ Cst) {
  int o = blockIdx.x;
  int tid = threadIdx.x;
  __shared__ float Ul[DN];
  __shared__ float red[512];
  __shared__ float swq[288], swp[288], sac[OCH], scc[OCH];
  for (int idx = tid; idx < 288; idx += 512) { swq[idx] = wq[idx]; swp[idx] = wp[idx]; }
  if (tid < OCH) { sac[tid] = acoef[tid]; scc[tid] = coefc[tid]; }
  if (tid < DN) Ul[tid] = 0.f;
  __syncthreads();

  float cacc = 0.f;
  bool act = tid < DN * DN;
  int i = tid / DN, j = tid % DN;
  if (act) {
    int icls = (i == 0) ? 0 : ((i == DN - 1) ? 2 : 1);
    int jcls = (j == 0) ? 0 : ((j == DN - 1) ? 2 : 1);
    const float* w1o = w1 + (size_t)o * (OCH * DN * DN) + i * DN + j;
    float uI = 0.f, uJ = 0.f, uIm = 0.f, uIp = 0.f, uJm = 0.f, uJp = 0.f;
    for (int c = 0; c < OCH; ++c) {
      float v = w1o[c * (DN * DN)];
      float a = sac[c];
      cacc += scc[c] * v;
      float av = a * v;
      uI += v;                                  // S row term (coeff 1)
      uJ += v;                                  // S col term (coeff 1)
      uIm += av * swq[(c * 3 + 0) * 3 + jcls];  // -> U[i-1]
      uI  += av * swq[(c * 3 + 1) * 3 + jcls];  // -> U[i]
      uIp += av * swq[(c * 3 + 2) * 3 + jcls];  // -> U[i+1]
      uJm += av * swp[(c * 3 + 0) * 3 + icls];  // -> U[j-1]
      uJ  += av * swp[(c * 3 + 1) * 3 + icls];  // -> U[j]
      uJp += av * swp[(c * 3 + 2) * 3 + icls];  // -> U[j+1]
    }
    atomicAdd(&Ul[i], uI);
    atomicAdd(&Ul[j], uJ);
    if (i > 0)      atomicAdd(&Ul[i - 1], uIm);
    if (i < DN - 1) atomicAdd(&Ul[i + 1], uIp);
    if (j > 0)      atomicAdd(&Ul[j - 1], uJm);
    if (j < DN - 1) atomicAdd(&Ul[j + 1], uJp);
  }
  red[tid] = cacc;
  __syncthreads();
  for (int st = 256; st > 0; st >>= 1) {
    if (tid < st) red[tid] += red[tid + st];
    __syncthreads();
  }
  if (tid == 0) Cst[o] = b1[o] + red[0];
  if (tid < DN) U[o * DN + tid] = Ul[tid];
}

// ---------------- K5: fused z = U*d + Cst, ReLU, FC2 ----------------
#define NPB 16
__global__ __launch_bounds__(256) void k_final(const float* __restrict__ dmat,
                                               const float* __restrict__ U,
                                               const float* __restrict__ Cst,
                                               const float* __restrict__ w2,
                                               const float* __restrict__ b2,
                                               float* __restrict__ out, int n_node) {
  __shared__ float dl[NPB][DN];
  __shared__ float h1s[NPB][H1DIM];
  int tid = threadIdx.x;
  int n0 = blockIdx.x * NPB;
  for (int idx = tid; idx < NPB * DN; idx += 256) {
    int ln = idx / DN, a = idx % DN;
    int nn = n0 + ln;
    dl[ln][a] = (nn < n_node) ? dmat[(size_t)nn * DN + a] : 0.f;
  }
  __syncthreads();
  for (int o = tid; o < H1DIM; o += 256) {
    float u[DN];
#pragma unroll
    for (int a = 0; a < DN; ++a) u[a] = U[o * DN + a];
    float cst = Cst[o];
    for (int ln = 0; ln < NPB; ++ln) {
      float z = cst;
#pragma unroll
      for (int a = 0; a < DN; ++a) z += u[a] * dl[ln][a];
      h1s[ln][o] = fmaxf(z, 0.f);
    }
  }
  __syncthreads();
  int k = tid & 63, sub = tid >> 6;
  if (k < H2DIM) {
    for (int ln = sub; ln < NPB; ln += 4) {
      int nn = n0 + ln;
      if (nn >= n_node) break;
      const float* wr = w2 + k * H1DIM;
      float acc = b2[k];
      for (int o = 0; o < H1DIM; ++o) acc += wr[o] * h1s[ln][o];
      out[(size_t)nn * H2DIM + k] = acc;
    }
  }
}

extern "C" void kernel_launch(void* const* d_in, const int* in_sizes, int n_in,
                              void* d_out, int out_size, void* d_ws, size_t ws_size,
                              hipStream_t stream) {
  const float* oe    = (const float*)d_in[0];
  const int*   nei   = (const int*)d_in[1];
  const int*   eai   = (const int*)d_in[2];
  const float* convw = (const float*)d_in[3];
  const float* convb = (const float*)d_in[4];
  const float* gamma = (const float*)d_in[5];
  const float* beta  = (const float*)d_in[6];
  const float* w1    = (const float*)d_in[7];
  const float* b1    = (const float*)d_in[8];
  const float* w2    = (const float*)d_in[9];
  const float* b2    = (const float*)d_in[10];
  float* out = (float*)d_out;
  float* ws  = (float*)d_ws;

  int n_ele  = in_sizes[1] / 4;
  int n_node = in_sizes[2] / 2;

  float* g     = ws + OFF_G;
  float* dmat  = ws + OFF_D;
  float* gsum  = ws + OFF_SUM;
  float* gssq  = ws + OFF_SSQ;
  float* acoef = ws + OFF_ACOEF;
  float* coefc = ws + OFF_COEFC;
  float* wq    = ws + OFF_WQ;
  float* wp    = ws + OFF_WP;
  float* U     = ws + OFF_U;
  float* Cst   = ws + OFF_CST;

  // zero the stat accumulators every call (ws is NOT re-poisoned between replays)
  hipMemsetAsync(gsum, 0, 64 * sizeof(float), stream);

  k_g<<<(n_ele + 255) / 256, 256, 0, stream>>>(oe, nei, g, n_ele);
  k_d<<<(n_node + 255) / 256, 256, 0, stream>>>(g, eai, dmat, n_node);
  k_stats<<<(n_node + 7) / 8, 256, 0, stream>>>(dmat, convw, convb, gsum, gssq, n_node);
  k_coef<<<1, 64, 0, stream>>>(gsum, gssq, convw, convb, gamma, beta,
                               acoef, coefc, wq, wp, n_node);
  k_buildU<<<H1DIM, 512, 0, stream>>>(w1, b1, acoef, coefc, wq, wp, U, Cst);
  k_final<<<(n_node + NPB - 1) / NPB, 256, 0, stream>>>(dmat, U, Cst, w2, b2, out, n_node);
}

// Round 2
// 134.252 us; speedup vs baseline: 1.1239x; 1.1239x over previous
//
#include <hip/hip_runtime.h>
#include <hip/hip_bf16.h>
#include <math.h>

#define NFEAT 17
#define DN 20
#define OCH 32
#define H1 500
#define H2 60

// ws float offsets (n_node=8192, n_ele=16384)
#define OFF_D      0         // 8192*20 = 163840
#define OFF_MOM    163840    // 230 (210 tri P + 20 s)
#define OFF_ACOEF  164096    // 32
#define OFF_COEFC  164128    // 32
#define OFF_WQ     164160    // 288
#define OFF_WP     164448    // 288
#define OFF_U      164736    // 500*20
#define OFF_CST    174736    // 500
#define OFF_W2T    175264    // 500*60
// total 205264 floats ~= 0.82 MB

// ---------- K1: fused g-gather + distribute + moment reduce (+w2 transpose tail blocks) ----
#define TB1 128
__global__ __launch_bounds__(TB1) void k_gd(const float* __restrict__ oe,
                                            const int* __restrict__ nei,
                                            const int* __restrict__ eai,
                                            const float* __restrict__ w2,
                                            float* __restrict__ dmat,
                                            float* __restrict__ mom,
                                            float* __restrict__ w2t, int n_node) {
  int nbd = (n_node + TB1 - 1) / TB1;
  if ((int)blockIdx.x >= nbd) {
    // spare blocks: transpose w2 (60x500) -> w2t (500x60)
    int base = (blockIdx.x - nbd) * TB1 + threadIdx.x;
    for (int idx = base; idx < H1 * H2; idx += 32 * TB1) {
      int k = idx / H1, o = idx % H1;
      w2t[o * H2 + k] = w2[idx];
    }
    return;
  }
  __shared__ float dls[TB1][DN + 1];
  int tid = threadIdx.x;
  int n = blockIdx.x * TB1 + tid;

  float d[DN];
#pragma unroll
  for (int k = 0; k < DN; ++k) d[k] = 0.f;

  if (n < n_node) {
    float h[NFEAT];
#pragma unroll
    for (int f = 0; f < NFEAT; ++f) h[f] = 0.f;
    for (int t = 0; t < 2; ++t) {
      int e = eai[n * 2 + t];
      float acc[NFEAT];
#pragma unroll
      for (int f = 0; f < NFEAT; ++f) acc[f] = 0.f;
#pragma unroll
      for (int m = 0; m < 4; ++m) {
        int a = nei[e * 4 + m];
        const float* row = oe + (size_t)a * NFEAT;
#pragma unroll
        for (int f = 0; f < NFEAT; ++f) acc[f] += row[f];
      }
      float nrm = 0.f;
#pragma unroll
      for (int f = 0; f < NFEAT; ++f) { float v = acc[f] * 0.25f; acc[f] = v; nrm += v * v; }
      float inv = 1.0f / sqrtf(nrm);
#pragma unroll
      for (int f = 0; f < NFEAT; ++f) h[f] += acc[f] * inv;
    }
    // distribute
    const float step = 50.0f / 19.0f;
    const float inv2 = 1.0f / (2.0f * 0.3f * 0.3f);
    float s[DN];
#pragma unroll
    for (int k = 0; k < DN; ++k) s[k] = 0.f;
    for (int f = 0; f < NFEAT; ++f) {
      float y = h[f];
      if (!(y > 0.0f && y < 110.0f)) continue;
      float ek[DN];
      float m = 0.f;
#pragma unroll
      for (int k = 0; k < DN; ++k) {
        float t2 = step * (float)k - y;
        ek[k] = __expf(-t2 * t2 * inv2);
        m = fmaxf(m, ek[k]);
      }
      if (m > 0.f) {
        float im = 1.0f / m;
#pragma unroll
        for (int k = 0; k < DN; ++k) s[k] += ek[k] * im;
      }
    }
    float smax = 0.f;
#pragma unroll
    for (int k = 0; k < DN; ++k) smax = fmaxf(smax, s[k]);
    float ism = (smax > 0.f) ? 1.0f / smax : 1.0f;
#pragma unroll
    for (int k = 0; k < DN; ++k) {
      d[k] = s[k] * ism;
      dmat[(size_t)n * DN + k] = d[k];
    }
  }
#pragma unroll
  for (int k = 0; k < DN; ++k) dls[tid][k] = d[k];
  __syncthreads();

  // block-level moment reduce: 210 triangular P entries + 20 sums
  for (int u = tid; u < 230; u += TB1) {
    float acc = 0.f;
    if (u < 210) {
      int a = 0, rem = u;
      while (rem >= DN - a) { rem -= DN - a; ++a; }
      int b = a + rem;
      for (int l = 0; l < TB1; ++l) acc += dls[l][a] * dls[l][b];
    } else {
      int a = u - 210;
      for (int l = 0; l < TB1; ++l) acc += dls[l][a];
    }
    atomicAdd(&mom[u], acc);
  }
}

// ---------- K2: BN stats from moments + coef tables (one block per channel) ----------
__global__ __launch_bounds__(512) void k_coef(const float* __restrict__ mom,
                                              const float* __restrict__ convw,
                                              const float* __restrict__ convb,
                                              const float* __restrict__ gamma,
                                              const float* __restrict__ beta,
                                              float* __restrict__ acoef,
                                              float* __restrict__ coefc,
                                              float* __restrict__ wq,
                                              float* __restrict__ wp, int n_node) {
  int c = blockIdx.x;
  int tid = threadIdx.x;
  __shared__ float P[DN * DN];
  __shared__ float S[DN];
  __shared__ float red1[512], red2[512];
  if (tid < 210) {
    int a = 0, rem = tid;
    while (rem >= DN - a) { rem -= DN - a; ++a; }
    int b = a + rem;
    float v = mom[tid];
    P[a * DN + b] = v; P[b * DN + a] = v;
  } else if (tid < 230) {
    S[tid - 210] = mom[tid];
  }
  __syncthreads();

  float w[3][3];
#pragma unroll
  for (int p = 0; p < 3; ++p)
#pragma unroll
    for (int q = 0; q < 3; ++q) w[p][q] = convw[c * 9 + p * 3 + q];
  float b_c = convb[c];

  float ssq = 0.f, sm = 0.f;
  if (tid < DN * DN) {
    int i = tid / DN, j = tid % DN;
    bool iv[3] = { i > 0, true, i < DN - 1 };
    bool jv[3] = { j > 0, true, j < DN - 1 };
    int idxs[6]; float cf[6]; int nt = 0;
#pragma unroll
    for (int p = 0; p < 3; ++p) if (iv[p]) {
      float cc = 0.f;
#pragma unroll
      for (int q = 0; q < 3; ++q) if (jv[q]) cc += w[p][q];
      idxs[nt] = i - 1 + p; cf[nt] = cc; ++nt;
    }
#pragma unroll
    for (int q = 0; q < 3; ++q) if (jv[q]) {
      float cc = 0.f;
#pragma unroll
      for (int p = 0; p < 3; ++p) if (iv[p]) cc += w[p][q];
      idxs[nt] = j - 1 + q; cf[nt] = cc; ++nt;
    }
    float q1 = 0.f, q2 = 0.f;
    for (int u = 0; u < nt; ++u) {
      q2 += cf[u] * S[idxs[u]];
      for (int v2 = 0; v2 < nt; ++v2)
        q1 += cf[u] * cf[v2] * P[idxs[u] * DN + idxs[v2]];
    }
    ssq = q1 + 2.f * b_c * q2;
    sm = q2;
  }
  red1[tid] = ssq; red2[tid] = sm;
  __syncthreads();
  for (int st = 256; st > 0; st >>= 1) {
    if (tid < st) { red1[tid] += red1[tid + st]; red2[tid] += red2[tid + st]; }
    __syncthreads();
  }
  if (tid == 0) {
    float Nt = (float)n_node * 400.f;
    float S1 = red2[0] + Nt * b_c;
    float S2 = red1[0] + Nt * b_c * b_c;
    float mu = S1 / Nt;
    float var = S2 / Nt - mu * mu;
    float a = gamma[c] / sqrtf(var + 1e-5f);
    acoef[c] = a;
    coefc[c] = a * (b_c - mu) + beta[c];
  }
  if (tid < 9) {
    int p = tid / 3, cls = tid % 3;
    float v = (cls == 0) ? (w[p][1] + w[p][2])
            : (cls == 1) ? (w[p][0] + w[p][1] + w[p][2])
                         : (w[p][0] + w[p][1]);
    wq[(c * 3 + p) * 3 + cls] = v;
  } else if (tid < 18) {
    int q = (tid - 9) / 3, cls = (tid - 9) % 3;
    float v = (cls == 0) ? (w[1][q] + w[2][q])
            : (cls == 1) ? (w[0][q] + w[1][q] + w[2][q])
                         : (w[0][q] + w[1][q]);
    wp[(c * 3 + q) * 3 + cls] = v;
  }
}

// ---------- K3: collapse conv+BN+FC1 weights: U[o,a], Cst[o] ----------
__global__ __launch_bounds__(512) void k_buildU(const float* __restrict__ w1,
                                                const float* __restrict__ b1,
                                                const float* __restrict__ acoef,
                                                const float* __restrict__ coefc,
                                                const float* __restrict__ wq,
                                                const float* __restrict__ wp,
                                                float* __restrict__ U,
                                                float* __restrict__ Cst) {
  int o = blockIdx.x;
  int tid = threadIdx.x;
  __shared__ float Ul[DN];
  __shared__ float red[512];
  __shared__ float swq[288], swp[288], sac[OCH], scc[OCH];
  for (int idx = tid; idx < 288; idx += 512) { swq[idx] = wq[idx]; swp[idx] = wp[idx]; }
  if (tid < OCH) { sac[tid] = acoef[tid]; scc[tid] = coefc[tid]; }
  if (tid < DN) Ul[tid] = 0.f;
  __syncthreads();

  float cacc = 0.f;
  bool act = tid < DN * DN;
  int i = tid / DN, j = tid % DN;
  if (act) {
    int icls = (i == 0) ? 0 : ((i == DN - 1) ? 2 : 1);
    int jcls = (j == 0) ? 0 : ((j == DN - 1) ? 2 : 1);
    const float* w1o = w1 + (size_t)o * (OCH * DN * DN) + i * DN + j;
    float uI = 0.f, uJ = 0.f, uIm = 0.f, uIp = 0.f, uJm = 0.f, uJp = 0.f;
    for (int c = 0; c < OCH; ++c) {
      float v = w1o[c * (DN * DN)];
      float a = sac[c];
      cacc += scc[c] * v;
      float av = a * v;
      uI += v;
      uJ += v;
      uIm += av * swq[(c * 3 + 0) * 3 + jcls];
      uI  += av * swq[(c * 3 + 1) * 3 + jcls];
      uIp += av * swq[(c * 3 + 2) * 3 + jcls];
      uJm += av * swp[(c * 3 + 0) * 3 + icls];
      uJ  += av * swp[(c * 3 + 1) * 3 + icls];
      uJp += av * swp[(c * 3 + 2) * 3 + icls];
    }
    atomicAdd(&Ul[i], uI);
    atomicAdd(&Ul[j], uJ);
    if (i > 0)      atomicAdd(&Ul[i - 1], uIm);
    if (i < DN - 1) atomicAdd(&Ul[i + 1], uIp);
    if (j > 0)      atomicAdd(&Ul[j - 1], uJm);
    if (j < DN - 1) atomicAdd(&Ul[j + 1], uJp);
  }
  red[tid] = cacc;
  __syncthreads();
  for (int st = 256; st > 0; st >>= 1) {
    if (tid < st) red[tid] += red[tid + st];
    __syncthreads();
  }
  if (tid == 0) Cst[o] = b1[o] + red[0];
  if (tid < DN) U[o * DN + tid] = Ul[tid];
}

// ---------- K4: fused FC1(rank-20) + ReLU + FC2, o-split across waves ----------
// block = 512 threads = 64 nodes x 8 o-segments; o uniform per wave -> scalar loads.
#define LP 61  // padded LDS row stride for the 60 outputs
__global__ __launch_bounds__(512) void k_final(const float* __restrict__ dmat,
                                               const float* __restrict__ U,
                                               const float* __restrict__ Cst,
                                               const float* __restrict__ w2t,
                                               const float* __restrict__ b2,
                                               float* __restrict__ out, int n_node) {
  __shared__ float lout[64 * LP];
  int tid = threadIdx.x;
  int lane = tid & 63;
  int oseg = __builtin_amdgcn_readfirstlane(tid >> 6);
  int n0 = blockIdx.x * 64;
  int n = n0 + lane;

  float d0[DN];
#pragma unroll
  for (int a = 0; a < DN; ++a) d0[a] = 0.f;
  if (n < n_node) {
    const float4* dr = (const float4*)(dmat + (size_t)n * DN);
    float4 v0 = dr[0], v1 = dr[1], v2 = dr[2], v3 = dr[3], v4 = dr[4];
    d0[0] = v0.x; d0[1] = v0.y; d0[2] = v0.z; d0[3] = v0.w;
    d0[4] = v1.x; d0[5] = v1.y; d0[6] = v1.z; d0[7] = v1.w;
    d0[8] = v2.x; d0[9] = v2.y; d0[10] = v2.z; d0[11] = v2.w;
    d0[12] = v3.x; d0[13] = v3.y; d0[14] = v3.z; d0[15] = v3.w;
    d0[16] = v4.x; d0[17] = v4.y; d0[18] = v4.z; d0[19] = v4.w;
  }
  for (int idx = tid; idx < 64 * LP; idx += 512) lout[idx] = 0.f;
  __syncthreads();

  int o0 = oseg * 63;
  int oend = (o0 + 63 < H1) ? (o0 + 63) : H1;
  float acc[H2];
#pragma unroll
  for (int k = 0; k < H2; ++k) acc[k] = 0.f;

  for (int o = o0; o < oend; ++o) {
    const float* Ur = U + o * DN;
    float z = Cst[o];
#pragma unroll
    for (int a = 0; a < DN; ++a) z += Ur[a] * d0[a];
    z = fmaxf(z, 0.f);
    const float* wr = w2t + o * H2;
#pragma unroll
    for (int k = 0; k < H2; ++k) acc[k] += wr[k] * z;
  }
#pragma unroll
  for (int k = 0; k < H2; ++k) atomicAdd(&lout[lane * LP + k], acc[k]);
  __syncthreads();

  int lim = (n_node - n0 < 64 ? n_node - n0 : 64) * H2;
  for (int idx = tid; idx < lim; idx += 512) {
    int nn = idx / H2, k = idx % H2;
    out[(size_t)n0 * H2 + idx] = lout[nn * LP + k] + b2[k];
  }
}

extern "C" void kernel_launch(void* const* d_in, const int* in_sizes, int n_in,
                              void* d_out, int out_size, void* d_ws, size_t ws_size,
                              hipStream_t stream) {
  const float* oe    = (const float*)d_in[0];
  const int*   nei   = (const int*)d_in[1];
  const int*   eai   = (const int*)d_in[2];
  const float* convw = (const float*)d_in[3];
  const float* convb = (const float*)d_in[4];
  const float* gamma = (const float*)d_in[5];
  const float* beta  = (const float*)d_in[6];
  const float* w1    = (const float*)d_in[7];
  const float* b1    = (const float*)d_in[8];
  const float* w2    = (const float*)d_in[9];
  const float* b2    = (const float*)d_in[10];
  float* out = (float*)d_out;
  float* ws  = (float*)d_ws;

  int n_node = in_sizes[2] / 2;

  float* dmat  = ws + OFF_D;
  float* mom   = ws + OFF_MOM;
  float* acoef = ws + OFF_ACOEF;
  float* coefc = ws + OFF_COEFC;
  float* wq    = ws + OFF_WQ;
  float* wp    = ws + OFF_WP;
  float* U     = ws + OFF_U;
  float* Cst   = ws + OFF_CST;
  float* w2t   = ws + OFF_W2T;

  hipMemsetAsync(mom, 0, 230 * sizeof(float), stream);

  int nbd = (n_node + TB1 - 1) / TB1;
  k_gd<<<nbd + 32, TB1, 0, stream>>>(oe, nei, eai, w2, dmat, mom, w2t, n_node);
  k_coef<<<OCH, 512, 0, stream>>>(mom, convw, convb, gamma, beta,
                                  acoef, coefc, wq, wp, n_node);
  k_buildU<<<H1, 512, 0, stream>>>(w1, b1, acoef, coefc, wq, wp, U, Cst);
  k_final<<<(n_node + 63) / 64, 512, 0, stream>>>(dmat, U, Cst, w2t, b2, out, n_node);
}

// Round 5
// 131.231 us; speedup vs baseline: 1.1497x; 1.0230x over previous
//
#include <hip/hip_runtime.h>
#include <hip/hip_bf16.h>
#include <math.h>

#define NFEAT 17
#define DN 20
#define OCH 32
#define H1 500
#define H2 60

// ws float offsets
#define OFF_D      0         // 8192*20 = 163840
#define OFF_MOMP   163840    // 256 blocks * 232 = 59392 partial moments
#define OFF_ACOEF  223232    // 32
#define OFF_COEFC  223264    // 32
#define OFF_WQ     223296    // 288
#define OFF_WP     223584    // 288
#define OFF_U      223872    // 500*20 = 10000
#define OFF_CST    233872    // 512
#define OFF_W2H    234384    // 2*500*32 = 32000 (padded w2 transpose halves)
// total 266384 floats ~= 1.07 MB

// ---------- K1: fused g-gather + distribute + per-block moment partials ----------
// 2 threads per node (one per element gather, split distribute f-range).
// Tail blocks: w2 -> padded transposed halves w2h, and wq/wp tap tables.
#define TB1 128
__global__ __launch_bounds__(TB1) void k_gd(const float* __restrict__ oe,
                                            const int* __restrict__ nei,
                                            const int* __restrict__ eai,
                                            const float* __restrict__ w2,
                                            const float* __restrict__ convw,
                                            float* __restrict__ dmat,
                                            float* __restrict__ momp,
                                            float* __restrict__ w2h,
                                            float* __restrict__ wq,
                                            float* __restrict__ wp, int n_node) {
  int nbd = (n_node + 63) / 64;
  int tid = threadIdx.x;
  if ((int)blockIdx.x >= nbd) {
    int tb = blockIdx.x - nbd;
    if (tb < 32) {
      for (int idx = tb * TB1 + tid; idx < 2 * H1 * 32; idx += 32 * TB1) {
        int h = idx / (H1 * 32);
        int r = idx - h * (H1 * 32);
        int o = r >> 5, j = r & 31;
        w2h[idx] = (j < 30) ? w2[(size_t)(h * 30 + j) * H1 + o] : 0.f;
      }
    } else if (tid < OCH) {
      int c = tid;
      float w[3][3];
#pragma unroll
      for (int p = 0; p < 3; ++p)
#pragma unroll
        for (int q = 0; q < 3; ++q) w[p][q] = convw[c * 9 + p * 3 + q];
#pragma unroll
      for (int p = 0; p < 3; ++p) {
        wq[(c * 3 + p) * 3 + 0] = w[p][1] + w[p][2];
        wq[(c * 3 + p) * 3 + 1] = w[p][0] + w[p][1] + w[p][2];
        wq[(c * 3 + p) * 3 + 2] = w[p][0] + w[p][1];
      }
#pragma unroll
      for (int q = 0; q < 3; ++q) {
        wp[(c * 3 + q) * 3 + 0] = w[1][q] + w[2][q];
        wp[(c * 3 + q) * 3 + 1] = w[0][q] + w[1][q] + w[2][q];
        wp[(c * 3 + q) * 3 + 2] = w[0][q] + w[1][q];
      }
    }
    return;
  }

  __shared__ float dls[64][21];
  int nl = tid >> 1, half = tid & 1;
  int n = blockIdx.x * 64 + nl;

  // gather one element's g-row
  float v[NFEAT];
#pragma unroll
  for (int f = 0; f < NFEAT; ++f) v[f] = 0.f;
  if (n < n_node) {
    int e = eai[(size_t)n * 2 + half];
    float a4[NFEAT];
#pragma unroll
    for (int f = 0; f < NFEAT; ++f) a4[f] = 0.f;
#pragma unroll
    for (int m = 0; m < 4; ++m) {
      int at = nei[(size_t)e * 4 + m];
      const float* row = oe + (size_t)at * NFEAT;
#pragma unroll
      for (int f = 0; f < NFEAT; ++f) a4[f] += row[f];
    }
    float nrm = 0.f;
#pragma unroll
    for (int f = 0; f < NFEAT; ++f) { float t = a4[f] * 0.25f; a4[f] = t; nrm += t * t; }
    float inv = 1.0f / sqrtf(nrm);
#pragma unroll
    for (int f = 0; f < NFEAT; ++f) v[f] = a4[f] * inv;
  }
  float h[NFEAT];
#pragma unroll
  for (int f = 0; f < NFEAT; ++f) h[f] = v[f] + __shfl_xor(v[f], 1);

  // distribute: this thread covers f in [f0,f1)
  const float step = 50.0f / 19.0f;
  const float inv2 = 1.0f / (2.0f * 0.3f * 0.3f);
  float s[DN];
#pragma unroll
  for (int k = 0; k < DN; ++k) s[k] = 0.f;
  int f0 = half ? 9 : 0, f1 = half ? NFEAT : 9;
  for (int f = f0; f < f1; ++f) {
    float y = h[f];
    if (!(y > 0.0f && y < 110.0f)) continue;
    float ek[DN];
    float m = 0.f;
#pragma unroll
    for (int k = 0; k < DN; ++k) {
      float t2 = step * (float)k - y;
      ek[k] = __expf(-t2 * t2 * inv2);
      m = fmaxf(m, ek[k]);
    }
    if (m > 0.f) {
      float im = 1.0f / m;
#pragma unroll
      for (int k = 0; k < DN; ++k) s[k] += ek[k] * im;
    }
  }
#pragma unroll
  for (int k = 0; k < DN; ++k) s[k] += __shfl_xor(s[k], 1);
  float smax = 0.f;
#pragma unroll
  for (int k = 0; k < DN; ++k) smax = fmaxf(smax, s[k]);
  float ism = (smax > 0.f) ? 1.0f / smax : 1.0f;

#pragma unroll
  for (int k = 0; k < 10; ++k) {
    float dv = s[half * 10 + k] * ism;
    dls[nl][half * 10 + k] = dv;
    if (n < n_node) dmat[(size_t)n * DN + half * 10 + k] = dv;
  }
  __syncthreads();

  // per-block moment partials: 210 tri P + 20 sums
  for (int u = tid; u < 230; u += TB1) {
    float acc = 0.f;
    if (u < 210) {
      int a = 0, rem = u;
      while (rem >= DN - a) { rem -= DN - a; ++a; }
      int b = a + rem;
      for (int l = 0; l < 64; ++l) acc += dls[l][a] * dls[l][b];
    } else {
      int a = u - 210;
      for (int l = 0; l < 64; ++l) acc += dls[l][a];
    }
    momp[(size_t)blockIdx.x * 232 + u] = acc;
  }
}

// ---------- K2: reduce moment partials + BN stats (one block per channel) ----------
__global__ __launch_bounds__(512) void k_coef(const float* __restrict__ momp, int nbd,
                                              const float* __restrict__ convw,
                                              const float* __restrict__ convb,
                                              const float* __restrict__ gamma,
                                              const float* __restrict__ beta,
                                              float* __restrict__ acoef,
                                              float* __restrict__ coefc, int n_node) {
  int c = blockIdx.x;
  int tid = threadIdx.x;
  __shared__ float P[DN * DN];
  __shared__ float S[DN];
  __shared__ float red1[512], red2[512];
  if (tid < 230) {
    float acc = 0.f;
    for (int b = 0; b < nbd; ++b) acc += momp[(size_t)b * 232 + tid];
    if (tid < 210) {
      int a = 0, rem = tid;
      while (rem >= DN - a) { rem -= DN - a; ++a; }
      int b = a + rem;
      P[a * DN + b] = acc; P[b * DN + a] = acc;
    } else {
      S[tid - 210] = acc;
    }
  }
  __syncthreads();

  float w[3][3];
#pragma unroll
  for (int p = 0; p < 3; ++p)
#pragma unroll
    for (int q = 0; q < 3; ++q) w[p][q] = convw[c * 9 + p * 3 + q];
  float b_c = convb[c];

  float ssq = 0.f, sm = 0.f;
  if (tid < DN * DN) {
    int i = tid / DN, j = tid % DN;
    bool iv[3] = { i > 0, true, i < DN - 1 };
    bool jv[3] = { j > 0, true, j < DN - 1 };
    int idxs[6]; float cf[6]; int nt = 0;
#pragma unroll
    for (int p = 0; p < 3; ++p) if (iv[p]) {
      float cc = 0.f;
#pragma unroll
      for (int q = 0; q < 3; ++q) if (jv[q]) cc += w[p][q];
      idxs[nt] = i - 1 + p; cf[nt] = cc; ++nt;
    }
#pragma unroll
    for (int q = 0; q < 3; ++q) if (jv[q]) {
      float cc = 0.f;
#pragma unroll
      for (int p = 0; p < 3; ++p) if (iv[p]) cc += w[p][q];
      idxs[nt] = j - 1 + q; cf[nt] = cc; ++nt;
    }
    float q1 = 0.f, q2 = 0.f;
    for (int u = 0; u < nt; ++u) {
      q2 += cf[u] * S[idxs[u]];
      for (int v2 = 0; v2 < nt; ++v2)
        q1 += cf[u] * cf[v2] * P[idxs[u] * DN + idxs[v2]];
    }
    ssq = q1 + 2.f * b_c * q2;
    sm = q2;
  }
  red1[tid] = ssq; red2[tid] = sm;
  __syncthreads();
  for (int st = 256; st > 0; st >>= 1) {
    if (tid < st) { red1[tid] += red1[tid + st]; red2[tid] += red2[tid + st]; }
    __syncthreads();
  }
  if (tid == 0) {
    float Nt = (float)n_node * 400.f;
    float S1 = red2[0] + Nt * b_c;
    float S2 = red1[0] + Nt * b_c * b_c;
    float mu = S1 / Nt;
    float var = S2 / Nt - mu * mu;
    float a = gamma[c] / sqrtf(var + 1e-5f);
    acoef[c] = a;
    coefc[c] = a * (b_c - mu) + beta[c];
  }
}

// ---------- K3: collapse conv+BN+FC1 weights: U[o,a], Cst[o] ----------
__global__ __launch_bounds__(512) void k_buildU(const float* __restrict__ w1,
                                                const float* __restrict__ b1,
                                                const float* __restrict__ acoef,
                                                const float* __restrict__ coefc,
                                                const float* __restrict__ wq,
                                                const float* __restrict__ wp,
                                                float* __restrict__ U,
                                                float* __restrict__ Cst) {
  int o = blockIdx.x;
  int tid = threadIdx.x;
  __shared__ float Ul[DN];
  __shared__ float red[512];
  __shared__ float swq[288], swp[288], sac[OCH], scc[OCH];
  for (int idx = tid; idx < 288; idx += 512) { swq[idx] = wq[idx]; swp[idx] = wp[idx]; }
  if (tid < OCH) { sac[tid] = acoef[tid]; scc[tid] = coefc[tid]; }
  if (tid < DN) Ul[tid] = 0.f;
  __syncthreads();

  float cacc = 0.f;
  bool act = tid < DN * DN;
  int i = tid / DN, j = tid % DN;
  if (act) {
    int icls = (i == 0) ? 0 : ((i == DN - 1) ? 2 : 1);
    int jcls = (j == 0) ? 0 : ((j == DN - 1) ? 2 : 1);
    const float* w1o = w1 + (size_t)o * (OCH * DN * DN) + i * DN + j;
    float uI = 0.f, uJ = 0.f, uIm = 0.f, uIp = 0.f, uJm = 0.f, uJp = 0.f;
    for (int c = 0; c < OCH; ++c) {
      float v = w1o[c * (DN * DN)];
      float a = sac[c];
      cacc += scc[c] * v;
      float av = a * v;
      uI += v;
      uJ += v;
      uIm += av * swq[(c * 3 + 0) * 3 + jcls];
      uI  += av * swq[(c * 3 + 1) * 3 + jcls];
      uIp += av * swq[(c * 3 + 2) * 3 + jcls];
      uJm += av * swp[(c * 3 + 0) * 3 + icls];
      uJ  += av * swp[(c * 3 + 1) * 3 + icls];
      uJp += av * swp[(c * 3 + 2) * 3 + icls];
    }
    atomicAdd(&Ul[i], uI);
    atomicAdd(&Ul[j], uJ);
    if (i > 0)      atomicAdd(&Ul[i - 1], uIm);
    if (i < DN - 1) atomicAdd(&Ul[i + 1], uIp);
    if (j > 0)      atomicAdd(&Ul[j - 1], uJm);
    if (j < DN - 1) atomicAdd(&Ul[j + 1], uJp);
  }
  red[tid] = cacc;
  __syncthreads();
  for (int st = 256; st > 0; st >>= 1) {
    if (tid < st) red[tid] += red[tid + st];
    __syncthreads();
  }
  if (tid == 0) Cst[o] = b1[o] + red[0];
  if (tid < DN) U[o * DN + tid] = Ul[tid];
}

// ---------- K4: fused FC1(rank-20)+ReLU+FC2 ----------
// block 256 = 4 waves (o-quarters); lane: n32 = lane&31 (node), khalf = lane>>5
// (which 30 of the 60 outputs). Per-thread state: d0[20] + acc[30] -> no spill.
__global__ __launch_bounds__(256, 1) void k_final(const float* __restrict__ dmat,
                                                  const float* __restrict__ U,
                                                  const float* __restrict__ Cst,
                                                  const float* __restrict__ w2h,
                                                  const float* __restrict__ b2,
                                                  float* __restrict__ out, int n_node) {
  __shared__ float lout[32 * 65];
  int tid = threadIdx.x;
  int wave = tid >> 6, lane = tid & 63;
  int n32 = lane & 31, khalf = lane >> 5;
  int n0 = blockIdx.x * 32;
  int n = n0 + n32;

  float d0[DN];
#pragma unroll
  for (int a = 0; a < DN; ++a) d0[a] = 0.f;
  if (n < n_node) {
    const float4* dr = (const float4*)(dmat + (size_t)n * DN);
#pragma unroll
    for (int q = 0; q < 5; ++q) {
      float4 t = dr[q];
      d0[q * 4 + 0] = t.x; d0[q * 4 + 1] = t.y;
      d0[q * 4 + 2] = t.z; d0[q * 4 + 3] = t.w;
    }
  }
  for (int idx = tid; idx < 32 * 65; idx += 256) lout[idx] = 0.f;
  __syncthreads();

  float acc[30];
#pragma unroll
  for (int j = 0; j < 30; ++j) acc[j] = 0.f;

  const float* wb = w2h + (size_t)khalf * (H1 * 32);
  int o0 = wave * 125;
#pragma unroll 2
  for (int t = 0; t < 125; ++t) {
    int o = o0 + t;
    float4 uv[5], wv[8];
    const float4* ur = (const float4*)(U + (size_t)o * DN);
#pragma unroll
    for (int q = 0; q < 5; ++q) uv[q] = ur[q];
    const float4* wr = (const float4*)(wb + (size_t)o * 32);
#pragma unroll
    for (int q = 0; q < 8; ++q) wv[q] = wr[q];
    float z = Cst[o];
#pragma unroll
    for (int q = 0; q < 5; ++q)
      z += uv[q].x * d0[q * 4 + 0] + uv[q].y * d0[q * 4 + 1] +
           uv[q].z * d0[q * 4 + 2] + uv[q].w * d0[q * 4 + 3];
    z = fmaxf(z, 0.f);
#pragma unroll
    for (int q = 0; q < 8; ++q) {
      int j = q * 4;
      if (j + 0 < 30) acc[j + 0] += wv[q].x * z;
      if (j + 1 < 30) acc[j + 1] += wv[q].y * z;
      if (j + 2 < 30) acc[j + 2] += wv[q].z * z;
      if (j + 3 < 30) acc[j + 3] += wv[q].w * z;
    }
  }
#pragma unroll
  for (int j = 0; j < 30; ++j)
    atomicAdd(&lout[n32 * 65 + khalf * 30 + j], acc[j]);
  __syncthreads();

  int rem = n_node - n0; if (rem > 32) rem = 32;
  int lim = rem * H2;
  for (int idx = tid; idx < lim; idx += 256) {
    int nn = idx / H2, k = idx - nn * H2;
    out[(size_t)n0 * H2 + idx] = lout[nn * 65 + k] + b2[k];
  }
}

extern "C" void kernel_launch(void* const* d_in, const int* in_sizes, int n_in,
                              void* d_out, int out_size, void* d_ws, size_t ws_size,
                              hipStream_t stream) {
  const float* oe    = (const float*)d_in[0];
  const int*   nei   = (const int*)d_in[1];
  const int*   eai   = (const int*)d_in[2];
  const float* convw = (const float*)d_in[3];
  const float* convb = (const float*)d_in[4];
  const float* gamma = (const float*)d_in[5];
  const float* beta  = (const float*)d_in[6];
  const float* w1    = (const float*)d_in[7];
  const float* b1    = (const float*)d_in[8];
  const float* w2    = (const float*)d_in[9];
  const float* b2    = (const float*)d_in[10];
  float* out = (float*)d_out;
  float* ws  = (float*)d_ws;

  int n_node = in_sizes[2] / 2;

  float* dmat  = ws + OFF_D;
  float* momp  = ws + OFF_MOMP;
  float* acoef = ws + OFF_ACOEF;
  float* coefc = ws + OFF_COEFC;
  float* wq    = ws + OFF_WQ;
  float* wp    = ws + OFF_WP;
  float* U     = ws + OFF_U;
  float* Cst   = ws + OFF_CST;
  float* w2h   = ws + OFF_W2H;

  int nbd = (n_node + 63) / 64;
  k_gd<<<nbd + 33, TB1, 0, stream>>>(oe, nei, eai, w2, convw,
                                     dmat, momp, w2h, wq, wp, n_node);
  k_coef<<<OCH, 512, 0, stream>>>(momp, nbd, convw, convb, gamma, beta,
                                  acoef, coefc, n_node);
  k_buildU<<<H1, 512, 0, stream>>>(w1, b1, acoef, coefc, wq, wp, U, Cst);
  k_final<<<(n_node + 31) / 32, 256, 0, stream>>>(dmat, U, Cst, w2h, b2, out, n_node);
}